// Round 3
// baseline (579.679 us; speedup 1.0000x reference)
//
#include <hip/hip_runtime.h>
#include <cstdint>
#include <cstddef>

typedef unsigned short u16;
typedef __bf16 bf16x8 __attribute__((ext_vector_type(8)));
typedef float f32x4 __attribute__((ext_vector_type(4)));
typedef short short8 __attribute__((ext_vector_type(8)));

#define DEVI static __device__ __forceinline__

DEVI u16 f2bf(float f) {
    unsigned u = __builtin_bit_cast(unsigned, f);
    u += 0x7fffu + ((u >> 16) & 1u);
    return (u16)(u >> 16);
}
DEVI float bf2f(u16 h) {
    unsigned u = ((unsigned)h) << 16;
    return __builtin_bit_cast(float, u);
}

namespace cfg {
constexpr int B = 2, T = 2048, BT = 4096, D = 2048, QL = 1536, KVL = 512, H = 16;
constexpr int DQK = 192, DROPE = 64, DV = 128, HD = H * DQK, KVD = H * 256;
}

// ---------------- f32 -> bf16 flat convert ----------------
__global__ void cvt_bf16_k(const float* __restrict__ in, u16* __restrict__ out, int n4) {
    for (int i = blockIdx.x * blockDim.x + threadIdx.x; i < n4; i += gridDim.x * blockDim.x) {
        float4 v = reinterpret_cast<const float4*>(in)[i];
        ushort4 o;
        o.x = f2bf(v.x); o.y = f2bf(v.y); o.z = f2bf(v.z); o.w = f2bf(v.w);
        reinterpret_cast<ushort4*>(out)[i] = o;
    }
}

// ---------- transpose+convert: in[R][C] f32 -> out[C][R] bf16 ----------
__global__ void transpose_cvt_k(const float* __restrict__ in, u16* __restrict__ out, int R, int C) {
    __shared__ float tile[32][33];
    int tx = threadIdx.x & 31, ty = threadIdx.x >> 5;  // 256 threads
    int c0 = blockIdx.x * 32, r0 = blockIdx.y * 32;
#pragma unroll
    for (int j = 0; j < 4; ++j)
        tile[ty + j * 8][tx] = in[(size_t)(r0 + ty + j * 8) * C + c0 + tx];
    __syncthreads();
#pragma unroll
    for (int j = 0; j < 4; ++j)
        out[(size_t)(c0 + ty + j * 8) * R + r0 + tx] = f2bf(tile[tx][ty + j * 8]);
}

// ---------------- RMSNorm (bf16 in, f32 w, bf16 out) ----------------
__global__ void rmsnorm_k(const u16* __restrict__ x, const float* __restrict__ w,
                          u16* __restrict__ y, int C) {
    int row = blockIdx.x, tid = threadIdx.x;
    const u16* xr = x + (size_t)row * C;
    u16* yr = y + (size_t)row * C;
    float ss = 0.f;
    for (int i = tid; i < C; i += 256) { float v = bf2f(xr[i]); ss += v * v; }
#pragma unroll
    for (int m = 32; m >= 1; m >>= 1) ss += __shfl_xor(ss, m);
    __shared__ float red[4];
    if ((tid & 63) == 0) red[tid >> 6] = ss;
    __syncthreads();
    float tot = red[0] + red[1] + red[2] + red[3];
    float rs = rsqrtf(tot / C + 1e-6f);
    for (int i = tid; i < C; i += 256) yr[i] = f2bf(bf2f(xr[i]) * rs * w[i]);
}

// ---------------- RoPE tables ----------------
__global__ void rope_tab_k(float* __restrict__ ct, float* __restrict__ st) {
    int idx = blockIdx.x * 256 + threadIdx.x;  // T*32 total
    int t = idx >> 5, i = idx & 31;
    float inv = powf(10000.f, -(float)i / 32.f);
    float f = (float)t * inv;
    ct[idx] = cosf(f);
    st[idx] = sinf(f);
}

// ---------------- RoPE apply (in-place on bf16 rows) ----------------
__global__ void rope_apply_k(u16* __restrict__ x, const float* __restrict__ ct,
                             const float* __restrict__ st, int nrows, int rstride,
                             int roff, int rows_per_t) {
    int idx = blockIdx.x * 256 + threadIdx.x;
    if (idx >= nrows * 32) return;
    int row = idx >> 5, i = idx & 31;
    int t = (row / rows_per_t) % cfg::T;
    u16* p = x + (size_t)row * rstride + roff;
    float x1 = bf2f(p[i]), x2 = bf2f(p[32 + i]);
    float c = ct[t * 32 + i], s = st[t * 32 + i];
    p[i] = f2bf(x1 * c - x2 * s);
    p[32 + i] = f2bf(x2 * c + x1 * s);
}

// ---------------- GEMM (small shapes): C = A * Bt^T, m97 structure ----------------
template <int BM, int BN, int BK, int WM, int WN, bool OUTF32>
__global__ __launch_bounds__((BM / WM) * (BN / WN) * 64) void gemm_bt_k(
    const u16* __restrict__ A, const u16* __restrict__ Bt, void* __restrict__ Cv,
    int M, int N, int K) {
    constexpr int NW = (BM / WM) * (BN / WN);
    constexpr int MFR = WM / 16, NFR = WN / 16;
    constexpr int NWN = BN / WN;
    __shared__ u16 As[BM * BK];
    __shared__ u16 Bs[BN * BK];
    const int tid = threadIdx.x, lane = tid & 63, wid = tid >> 6;
    const int wr = wid / NWN, wc = wid % NWN;
    const int tM = blockIdx.x * BM, tN = blockIdx.y * BN;
    const int lr = lane & 15, hi = lane >> 4;
    f32x4 acc[MFR][NFR] = {};
    for (int k0 = 0; k0 < K; k0 += BK) {
        constexpr int ACH = BM * BK * 2 / NW;  // bytes per wave
#pragma unroll
        for (int c = 0; c < ACH / 1024; ++c) {
            int loff = wid * ACH + c * 1024;
            int eidx = (loff >> 1) + lane * 8;
            const u16* src = A + (size_t)(tM + eidx / BK) * K + k0 + (eidx % BK);
            __builtin_amdgcn_global_load_lds(
                (const __attribute__((address_space(1))) void*)src,
                (__attribute__((address_space(3))) void*)((char*)As + loff), 16, 0, 0);
        }
        constexpr int BCH = BN * BK * 2 / NW;
#pragma unroll
        for (int c = 0; c < BCH / 1024; ++c) {
            int loff = wid * BCH + c * 1024;
            int eidx = (loff >> 1) + lane * 8;
            const u16* src = Bt + (size_t)(tN + eidx / BK) * K + k0 + (eidx % BK);
            __builtin_amdgcn_global_load_lds(
                (const __attribute__((address_space(1))) void*)src,
                (__attribute__((address_space(3))) void*)((char*)Bs + loff), 16, 0, 0);
        }
        __syncthreads();
#pragma unroll
        for (int kk = 0; kk < BK / 32; ++kk) {
            bf16x8 af[MFR], bfv[NFR];
#pragma unroll
            for (int mi = 0; mi < MFR; ++mi)
                af[mi] = *reinterpret_cast<const bf16x8*>(&As[(wr * WM + mi * 16 + lr) * BK + kk * 32 + hi * 8]);
#pragma unroll
            for (int ni = 0; ni < NFR; ++ni)
                bfv[ni] = *reinterpret_cast<const bf16x8*>(&Bs[(wc * WN + ni * 16 + lr) * BK + kk * 32 + hi * 8]);
#pragma unroll
            for (int mi = 0; mi < MFR; ++mi)
#pragma unroll
                for (int ni = 0; ni < NFR; ++ni)
                    acc[mi][ni] = __builtin_amdgcn_mfma_f32_16x16x32_bf16(af[mi], bfv[ni], acc[mi][ni], 0, 0, 0);
        }
        __syncthreads();
    }
#pragma unroll
    for (int mi = 0; mi < MFR; ++mi)
#pragma unroll
        for (int ni = 0; ni < NFR; ++ni)
#pragma unroll
            for (int r = 0; r < 4; ++r) {
                int row = tM + wr * WM + mi * 16 + hi * 4 + r;
                int col = tN + wc * WN + ni * 16 + lr;
                if (OUTF32)
                    ((float*)Cv)[(size_t)row * N + col] = acc[mi][ni][r];
                else
                    ((u16*)Cv)[(size_t)row * N + col] = f2bf(acc[mi][ni][r]);
            }
}

// ---------------- GEMM (big shapes): 256x256 8-phase, BK=64, 8 waves ----------------
// Double-buffered 128KB LDS; half-tile = 128x64 bf16 = 16KB; st_16x32 swizzle
// (byte ^= ((byte>>9)&1)<<5) applied on pre-swizzled global source AND ds_read.
// Stage schedule (iteration computes K-tiles u=2it [buf0] and u+1 [buf1]):
//   ph0,1: A(u+1)->buf1.A   ph2,3: B(u+2)->buf0.B
//   ph4,5: A(u+2)->buf0.A   ph6,7: B(u+3)->buf1.B
// Each stage's target region last-read >=1 barrier earlier; RAW covered by
// vmcnt(4) at end of ph3/ph7 only (2 newest half-tiles may stay in flight).
template <bool OUTF32>
__global__ __launch_bounds__(512, 2) void gemm8_k(const u16* __restrict__ A,
                                                  const u16* __restrict__ Bt,
                                                  void* __restrict__ Cv,
                                                  int M, int N, int K) {
    __shared__ __align__(16) char lds[131072];
    const int tid = threadIdx.x, lane = tid & 63, wid = tid >> 6;
    const int wr = wid >> 2, wc = wid & 3;  // 2M x 4N waves, per-wave C = 128x64
    const int lr = lane & 15, hi = lane >> 4;
    const int mt = M >> 8;
    const int nwg = gridDim.x;
    // bijective XCD swizzle (m204)
    int orig = blockIdx.x;
    int q8 = nwg >> 3, r8 = nwg & 7, xcd = orig & 7, id8 = orig >> 3;
    int wg = (xcd < r8 ? xcd * (q8 + 1) : r8 * (q8 + 1) + (xcd - r8) * q8) + id8;
    const int tM = (wg % mt) << 8, tN = (wg / mt) << 8;
    const size_t Ks = (size_t)K;

    f32x4 acc[8][4] = {};
    bf16x8 bfr[4][2];

    auto STAGE = [&](const u16* __restrict__ P, int row0, int k0, int ldsbase) {
#pragma unroll
        for (int c = 0; c < 2; ++c) {
            int doff = tid * 16 + c * 8192;                 // linear dest byte in half-tile
            int s = doff ^ (((doff >> 9) & 1) << 5);        // pre-swizzled source byte
            int e = s >> 1;                                 // bf16 element
            const u16* src = P + (size_t)(row0 + (e >> 6)) * Ks + (k0 + (e & 63));
            __builtin_amdgcn_global_load_lds(
                (const __attribute__((address_space(1))) void*)src,
                (__attribute__((address_space(3))) void*)(lds + ldsbase + (wid << 10) + (c << 13)),
                16, 0, 0);
        }
    };
    auto RDB = [&](int buf) {
#pragma unroll
        for (int ni = 0; ni < 4; ++ni)
#pragma unroll
            for (int kk = 0; kk < 2; ++kk) {
                int off = ((wc & 1) * 64 + ni * 16 + lr) * 128 + (kk * 32 + hi * 8) * 2;
                off ^= ((off >> 9) & 1) << 5;
                bfr[ni][kk] = *(const bf16x8*)(lds + buf * 65536 + 32768 + (wc >> 1) * 16384 + off);
            }
    };
    auto RDA = [&](int qd, int buf, bf16x8 af[2][2]) {
#pragma unroll
        for (int mi = 0; mi < 2; ++mi)
#pragma unroll
            for (int kk = 0; kk < 2; ++kk) {
                int off = (qd * 32 + mi * 16 + lr) * 128 + (kk * 32 + hi * 8) * 2;
                off ^= ((off >> 9) & 1) << 5;
                af[mi][kk] = *(const bf16x8*)(lds + buf * 65536 + wr * 16384 + off);
            }
    };
    auto MM = [&](int qd, bf16x8 af[2][2]) {
        __builtin_amdgcn_s_setprio(1);
#pragma unroll
        for (int kk = 0; kk < 2; ++kk)
#pragma unroll
            for (int mi = 0; mi < 2; ++mi)
#pragma unroll
                for (int ni = 0; ni < 4; ++ni)
                    acc[qd * 2 + mi][ni] = __builtin_amdgcn_mfma_f32_16x16x32_bf16(
                        af[mi][kk], bfr[ni][kk], acc[qd * 2 + mi][ni], 0, 0, 0);
        __builtin_amdgcn_s_setprio(0);
    };

#define G8_BARRIER asm volatile("s_barrier" ::: "memory")
#define G8_VMCNT4 asm volatile("s_waitcnt vmcnt(4)" ::: "memory")

    const int NIT = K >> 7;  // K-tiles / 2

    // prologue: A(0),B(0) -> buf0 ; B(1) -> buf1.B
    STAGE(A, tM, 0, 0);
    STAGE(A, tM + 128, 0, 16384);
    STAGE(Bt, tN, 0, 32768);
    STAGE(Bt, tN + 128, 0, 49152);
    STAGE(Bt, tN, 64, 65536 + 32768);
    STAGE(Bt, tN + 128, 64, 65536 + 49152);
    G8_VMCNT4;
    G8_BARRIER;

    for (int it = 0; it < NIT; ++it) {
        const int u = it * 2;
        const bool more = (it + 1 < NIT);
        bf16x8 af[2][2];
        // ---- K-tile u (buf0) ----
        RDB(0); RDA(0, 0, af);
        STAGE(A, tM, (u + 1) << 6, 65536);                     // A0(u+1)
        G8_BARRIER;
        MM(0, af);
        G8_BARRIER;
        RDA(1, 0, af);
        STAGE(A, tM + 128, (u + 1) << 6, 65536 + 16384);       // A1(u+1)
        G8_BARRIER;
        MM(1, af);
        G8_BARRIER;
        RDA(2, 0, af);
        if (more) STAGE(Bt, tN, (u + 2) << 6, 32768);          // B0(u+2)
        G8_BARRIER;
        MM(2, af);
        G8_BARRIER;
        RDA(3, 0, af);
        if (more) STAGE(Bt, tN + 128, (u + 2) << 6, 49152);    // B1(u+2)
        G8_BARRIER;
        MM(3, af);
        G8_VMCNT4;
        G8_BARRIER;
        // ---- K-tile u+1 (buf1) ----
        RDB(1); RDA(0, 1, af);
        if (more) STAGE(A, tM, (u + 2) << 6, 0);               // A0(u+2)
        G8_BARRIER;
        MM(0, af);
        G8_BARRIER;
        RDA(1, 1, af);
        if (more) STAGE(A, tM + 128, (u + 2) << 6, 16384);     // A1(u+2)
        G8_BARRIER;
        MM(1, af);
        G8_BARRIER;
        RDA(2, 1, af);
        if (more) STAGE(Bt, tN, (u + 3) << 6, 65536 + 32768);  // B0(u+3)
        G8_BARRIER;
        MM(2, af);
        G8_BARRIER;
        RDA(3, 1, af);
        if (more) STAGE(Bt, tN + 128, (u + 3) << 6, 65536 + 49152);  // B1(u+3)
        G8_BARRIER;
        MM(3, af);
        G8_VMCNT4;
        G8_BARRIER;
    }
#undef G8_BARRIER
#undef G8_VMCNT4

    // epilogue: acc[mi8][ni], row-in-wave = (mi8>>1)*32 + (mi8&1)*16 + hi*4 + r
#pragma unroll
    for (int mi8 = 0; mi8 < 8; ++mi8)
#pragma unroll
        for (int ni = 0; ni < 4; ++ni)
#pragma unroll
            for (int r = 0; r < 4; ++r) {
                int row = tM + wr * 128 + (mi8 >> 1) * 32 + (mi8 & 1) * 16 + hi * 4 + r;
                int col = tN + wc * 64 + ni * 16 + lr;
                if (OUTF32)
                    ((float*)Cv)[(size_t)row * N + col] = acc[mi8][ni][r];
                else
                    ((u16*)Cv)[(size_t)row * N + col] = f2bf(acc[mi8][ni][r]);
            }
}

// ---------------- Flash attention (causal, bf16, MFMA) ----------------
namespace acfg {
constexpr int QB = 64, KB = 64, KS = 200, VTS = 72, PS = 72;
constexpr int NQT = cfg::T / QB;  // 32
}
__global__ __launch_bounds__(256) void mla_attn_k(const u16* __restrict__ q,
                                                  const u16* __restrict__ kv,
                                                  const u16* __restrict__ kr,
                                                  u16* __restrict__ o) {
    using namespace cfg;
    using namespace acfg;
    __shared__ u16 Ks[KB * KS];       // 64 x 192 (stride 200)
    __shared__ u16 Vt[DV * VTS];      // 128 x 64 (stride 72), V transposed+swizzled
    __shared__ u16 Pl[4 * 16 * PS];   // per-wave 16 x 64 (stride 72)
    const int b = blockIdx.x >> 4, h = blockIdx.x & 15;
    const int pj = blockIdx.y;  // 0..NQT/2-1
    const int tid = threadIdx.x, lane = tid & 63, w = tid >> 6;
    const int lr = lane & 15, hi = lane >> 4;
    const float sc2 = 0.07216878364870323f * 1.4426950408889634f;  // 1/sqrt(192) * log2(e)

#pragma unroll 1
    for (int half = 0; half < 2; ++half) {
        const int qt = half ? (NQT - 1 - pj) : pj;
        const int q0 = qt * QB;
        bf16x8 qf[6];
        {
            int row = q0 + w * 16 + lr;
            const u16* qp = q + ((size_t)(b * T + row) * H + h) * DQK;
#pragma unroll
            for (int ks = 0; ks < 6; ++ks)
                qf[ks] = *reinterpret_cast<const bf16x8*>(qp + ks * 32 + hi * 8);
        }
        f32x4 oacc[8] = {};
        float mrow[4], lrow[4];
#pragma unroll
        for (int r = 0; r < 4; ++r) { mrow[r] = -INFINITY; lrow[r] = 0.f; }

        const int nkb = qt + 1;
#pragma unroll 1
        for (int kb = 0; kb < nkb; ++kb) {
            const int kt0 = kb * KB;
#pragma unroll
            for (int it = 0; it < 4; ++it) {
                int id = tid + it * 256, r = id >> 4, c8 = id & 15;
                short8 v = *reinterpret_cast<const short8*>(
                    kv + ((size_t)(b * T + kt0 + r) * H + h) * 256 + c8 * 8);
                *reinterpret_cast<short8*>(&Ks[r * KS + c8 * 8]) = v;
            }
#pragma unroll
            for (int it = 0; it < 2; ++it) {
                int id = tid + it * 256, r = id >> 3, c8 = id & 7;
                short8 v = *reinterpret_cast<const short8*>(
                    kr + (size_t)(b * T + kt0 + r) * DROPE + c8 * 8);
                *reinterpret_cast<short8*>(&Ks[r * KS + 128 + c8 * 8]) = v;
            }
#pragma unroll
            for (int it = 0; it < 4; ++it) {
                int id = tid + it * 256, r = id >> 4, c8 = id & 15;
                short8 v = *reinterpret_cast<const short8*>(
                    kv + ((size_t)(b * T + kt0 + r) * H + h) * 256 + 128 + c8 * 8);
                int teff = r ^ ((c8 & 7) << 3);
#pragma unroll
                for (int j = 0; j < 8; ++j) Vt[(c8 * 8 + j) * VTS + teff] = (u16)v[j];
            }
            __syncthreads();

            f32x4 s[4] = {};
#pragma unroll
            for (int ks = 0; ks < 6; ++ks) {
                bf16x8 kf[4];
#pragma unroll
                for (int ni = 0; ni < 4; ++ni)
                    kf[ni] = *reinterpret_cast<const bf16x8*>(&Ks[(ni * 16 + lr) * KS + ks * 32 + hi * 8]);
#pragma unroll
                for (int ni = 0; ni < 4; ++ni)
                    s[ni] = __builtin_amdgcn_mfma_f32_16x16x32_bf16(qf[ks], kf[ni], s[ni], 0, 0, 0);
            }
            const bool diag = (kb == nkb - 1);
#pragma unroll
            for (int r = 0; r < 4; ++r) {
                float mx = -INFINITY;
#pragma unroll
                for (int ni = 0; ni < 4; ++ni) {
                    float v = s[ni][r];
                    if (diag) {
                        int qr = q0 + w * 16 + hi * 4 + r;
                        int kc = kt0 + ni * 16 + lr;
                        if (kc > qr) v = -INFINITY;
                    }
                    s[ni][r] = v;
                    mx = fmaxf(mx, v);
                }
                mx = fmaxf(mx, __shfl_xor(mx, 1));
                mx = fmaxf(mx, __shfl_xor(mx, 2));
                mx = fmaxf(mx, __shfl_xor(mx, 4));
                mx = fmaxf(mx, __shfl_xor(mx, 8));
                float mold = mrow[r];
                float mnew = fmaxf(mold, mx);
                float alpha = exp2f((mold - mnew) * sc2);
                float sum = 0.f;
#pragma unroll
                for (int ni = 0; ni < 4; ++ni) {
                    float p = exp2f((s[ni][r] - mnew) * sc2);
                    s[ni][r] = p;
                    sum += p;
                }
                sum += __shfl_xor(sum, 1);
                sum += __shfl_xor(sum, 2);
                sum += __shfl_xor(sum, 4);
                sum += __shfl_xor(sum, 8);
                lrow[r] = lrow[r] * alpha + sum;
                mrow[r] = mnew;
#pragma unroll
                for (int ni = 0; ni < 8; ++ni) oacc[ni][r] *= alpha;
            }
            u16* pw = &Pl[w * 16 * PS];
#pragma unroll
            for (int ni = 0; ni < 4; ++ni)
#pragma unroll
                for (int r = 0; r < 4; ++r)
                    pw[(hi * 4 + r) * PS + ni * 16 + lr] = f2bf(s[ni][r]);
#pragma unroll
            for (int kk = 0; kk < 2; ++kk) {
                bf16x8 pf = *reinterpret_cast<const bf16x8*>(&pw[lr * PS + kk * 32 + hi * 8]);
#pragma unroll
                for (int ni = 0; ni < 8; ++ni) {
                    int d = ni * 16 + lr;
                    int teff = (kk * 32 + hi * 8) ^ (((d >> 3) & 7) << 3);
                    bf16x8 vf = *reinterpret_cast<const bf16x8*>(&Vt[d * VTS + teff]);
                    oacc[ni] = __builtin_amdgcn_mfma_f32_16x16x32_bf16(pf, vf, oacc[ni], 0, 0, 0);
                }
            }
            __syncthreads();
        }
#pragma unroll
        for (int ni = 0; ni < 8; ++ni)
#pragma unroll
            for (int r = 0; r < 4; ++r) {
                int row = q0 + w * 16 + hi * 4 + r;
                int col = ni * 16 + lr;
                float v = oacc[ni][r] / lrow[r];
                o[((size_t)(b * T + row) * H + h) * DV + col] = f2bf(v);
            }
    }
}

// ---------------- workspace layout ----------------
namespace wso {
using namespace cfg;
constexpr size_t O_HS   = 0;
constexpr size_t O_WQA  = O_HS   + (size_t)BT * D * 2;
constexpr size_t O_WQB  = O_WQA  + (size_t)QL * D * 2;
constexpr size_t O_WKVA = O_WQB  + (size_t)HD * QL * 2;
constexpr size_t O_WKVB = O_WKVA + (size_t)KVL * D * 2;
constexpr size_t O_WKR  = O_WKVB + (size_t)KVD * KVL * 2;
constexpr size_t O_WO   = O_WKR  + (size_t)DROPE * D * 2;
constexpr size_t O_QA   = O_WO   + (size_t)D * D * 2;
constexpr size_t O_QAN  = O_QA   + (size_t)BT * QL * 2;
constexpr size_t O_Q    = O_QAN  + (size_t)BT * QL * 2;
constexpr size_t O_KVA  = O_Q    + (size_t)BT * HD * 2;
constexpr size_t O_KVAN = O_KVA  + (size_t)BT * KVL * 2;
constexpr size_t O_KV   = O_KVAN + (size_t)BT * KVL * 2;
constexpr size_t O_KR   = O_KV   + (size_t)BT * KVD * 2;
constexpr size_t O_COS  = O_KR   + (size_t)BT * DROPE * 2;
constexpr size_t O_SIN  = O_COS  + (size_t)T * 32 * 4;
constexpr size_t O_O    = O_SIN  + (size_t)T * 32 * 4;
}

extern "C" void kernel_launch(void* const* d_in, const int* in_sizes, int n_in,
                              void* d_out, int out_size, void* d_ws, size_t ws_size,
                              hipStream_t stream) {
    using namespace cfg;
    using namespace wso;
    (void)in_sizes; (void)n_in; (void)out_size; (void)ws_size;

    const float* hs   = (const float*)d_in[0];
    const float* Wqa  = (const float*)d_in[1];
    const float* qnw  = (const float*)d_in[2];
    const float* Wqb  = (const float*)d_in[3];
    const float* Wkr  = (const float*)d_in[4];
    const float* Wkva = (const float*)d_in[5];
    const float* kvnw = (const float*)d_in[6];
    const float* Wkvb = (const float*)d_in[7];
    const float* Wo   = (const float*)d_in[8];

    char* ws = (char*)d_ws;
    u16* hs_b   = (u16*)(ws + O_HS);
    u16* wqa_t  = (u16*)(ws + O_WQA);
    u16* wqb_t  = (u16*)(ws + O_WQB);
    u16* wkva_t = (u16*)(ws + O_WKVA);
    u16* wkvb_t = (u16*)(ws + O_WKVB);
    u16* wkr_t  = (u16*)(ws + O_WKR);
    u16* wo_t   = (u16*)(ws + O_WO);
    u16* qa     = (u16*)(ws + O_QA);
    u16* qan    = (u16*)(ws + O_QAN);
    u16* qb     = (u16*)(ws + O_Q);
    u16* kva    = (u16*)(ws + O_KVA);
    u16* kvan   = (u16*)(ws + O_KVAN);
    u16* kvb    = (u16*)(ws + O_KV);
    u16* krb    = (u16*)(ws + O_KR);
    float* cost = (float*)(ws + O_COS);
    float* sint = (float*)(ws + O_SIN);
    u16* ob     = (u16*)(ws + O_O);

    // 1. convert hidden to bf16
    cvt_bf16_k<<<2048, 256, 0, stream>>>(hs, hs_b, BT * D / 4);
    // 2. transpose-convert weights: [K,N] f32 -> [N,K] bf16
    transpose_cvt_k<<<dim3(QL / 32, D / 32), 256, 0, stream>>>(Wqa, wqa_t, D, QL);
    transpose_cvt_k<<<dim3(HD / 32, QL / 32), 256, 0, stream>>>(Wqb, wqb_t, QL, HD);
    transpose_cvt_k<<<dim3(KVL / 32, D / 32), 256, 0, stream>>>(Wkva, wkva_t, D, KVL);
    transpose_cvt_k<<<dim3(KVD / 32, KVL / 32), 256, 0, stream>>>(Wkvb, wkvb_t, KVL, KVD);
    transpose_cvt_k<<<dim3(DROPE / 32, D / 32), 256, 0, stream>>>(Wkr, wkr_t, D, DROPE);
    transpose_cvt_k<<<dim3(D / 32, D / 32), 256, 0, stream>>>(Wo, wo_t, D, D);
    // 3. rope tables
    rope_tab_k<<<T * 32 / 256, 256, 0, stream>>>(cost, sint);
    // 4. q_a = hidden @ Wq_a ; rmsnorm   (gemm8: 16x6 = 96 wgs)
    gemm8_k<false><<<(BT / 256) * (QL / 256), 512, 0, stream>>>(hs_b, wqa_t, qa, BT, QL, D);
    rmsnorm_k<<<BT, 256, 0, stream>>>(qa, qnw, qan, QL);
    // 5. q = q_norm @ Wq_b ; rope        (gemm8: 16x12 = 192 wgs)
    gemm8_k<false><<<(BT / 256) * (HD / 256), 512, 0, stream>>>(qan, wqb_t, qb, BT, HD, QL);
    rope_apply_k<<<BT * H * 32 / 256, 256, 0, stream>>>(qb, cost, sint, BT * H, DQK, 128, H);
    // 6. kv_a = hidden @ Wkv_a (small N -> old kernel) ; rmsnorm ; kv_b (gemm8: 256 wgs)
    gemm_bt_k<128, 128, 32, 64, 64, false><<<dim3(BT / 128, KVL / 128), 256, 0, stream>>>(
        hs_b, wkva_t, kva, BT, KVL, D);
    rmsnorm_k<<<BT, 256, 0, stream>>>(kva, kvnw, kvan, KVL);
    gemm8_k<false><<<(BT / 256) * (KVD / 256), 512, 0, stream>>>(kvan, wkvb_t, kvb, BT, KVD, KVL);
    // 7. k_rope = hidden @ Wk_rope ; rope
    gemm_bt_k<128, 64, 32, 32, 64, false><<<dim3(BT / 128, 1), 256, 0, stream>>>(
        hs_b, wkr_t, krb, BT, DROPE, D);
    rope_apply_k<<<BT * 32 / 256, 256, 0, stream>>>(krb, cost, sint, BT, DROPE, 0, 1);
    // 8. attention (paired causal tiles, balanced)
    mla_attn_k<<<dim3(B * H, acfg::NQT / 2), 256, 0, stream>>>(qb, kvb, krb, ob);
    // 9. out = o @ Wo  (f32 out, gemm8: 16x8 = 128 wgs)
    gemm8_k<true><<<(BT / 256) * (D / 256), 512, 0, stream>>>(ob, wo_t, d_out, BT, D, H * DV);
}

// Round 4
// 510.960 us; speedup vs baseline: 1.1345x; 1.1345x over previous
//
#include <hip/hip_runtime.h>
#include <cstdint>
#include <cstddef>

typedef unsigned short u16;
typedef __bf16 bf16x8 __attribute__((ext_vector_type(8)));
typedef float f32x4 __attribute__((ext_vector_type(4)));
typedef short short8 __attribute__((ext_vector_type(8)));

#define DEVI static __device__ __forceinline__

DEVI u16 f2bf(float f) {
    unsigned u = __builtin_bit_cast(unsigned, f);
    u += 0x7fffu + ((u >> 16) & 1u);
    return (u16)(u >> 16);
}
DEVI float bf2f(u16 h) {
    unsigned u = ((unsigned)h) << 16;
    return __builtin_bit_cast(float, u);
}

namespace cfg {
constexpr int B = 2, T = 2048, BT = 4096, D = 2048, QL = 1536, KVL = 512, H = 16;
constexpr int DQK = 192, DROPE = 64, DV = 128, HD = H * DQK, KVD = H * 256;
constexpr int NCAT = 2176;  // QL + KVL + DROPE (2112) padded to 17*128
}

// ---------------- f32 -> bf16 flat convert ----------------
__global__ void cvt_bf16_k(const float* __restrict__ in, u16* __restrict__ out, int n4) {
    for (int i = blockIdx.x * blockDim.x + threadIdx.x; i < n4; i += gridDim.x * blockDim.x) {
        float4 v = reinterpret_cast<const float4*>(in)[i];
        ushort4 o;
        o.x = f2bf(v.x); o.y = f2bf(v.y); o.z = f2bf(v.z); o.w = f2bf(v.w);
        reinterpret_cast<ushort4*>(out)[i] = o;
    }
}

// ---------- transpose+convert: in[R][C] f32 -> out[C][R] bf16 ----------
__global__ void transpose_cvt_k(const float* __restrict__ in, u16* __restrict__ out, int R, int C) {
    __shared__ float tile[32][33];
    int tx = threadIdx.x & 31, ty = threadIdx.x >> 5;  // 256 threads
    int c0 = blockIdx.x * 32, r0 = blockIdx.y * 32;
#pragma unroll
    for (int j = 0; j < 4; ++j)
        tile[ty + j * 8][tx] = in[(size_t)(r0 + ty + j * 8) * C + c0 + tx];
    __syncthreads();
#pragma unroll
    for (int j = 0; j < 4; ++j)
        out[(size_t)(c0 + ty + j * 8) * R + r0 + tx] = f2bf(tile[tx][ty + j * 8]);
}

// ---------------- RMSNorm (bf16 in, f32 w, bf16 out), strided input ----------------
__global__ void rmsnorm_k(const u16* __restrict__ x, const float* __restrict__ w,
                          u16* __restrict__ y, int C, int xs) {
    int row = blockIdx.x, tid = threadIdx.x;
    const u16* xr = x + (size_t)row * xs;
    u16* yr = y + (size_t)row * C;
    float ss = 0.f;
    for (int i = tid; i < C; i += 256) { float v = bf2f(xr[i]); ss += v * v; }
#pragma unroll
    for (int m = 32; m >= 1; m >>= 1) ss += __shfl_xor(ss, m);
    __shared__ float red[4];
    if ((tid & 63) == 0) red[tid >> 6] = ss;
    __syncthreads();
    float tot = red[0] + red[1] + red[2] + red[3];
    float rs = rsqrtf(tot / C + 1e-6f);
    for (int i = tid; i < C; i += 256) yr[i] = f2bf(bf2f(xr[i]) * rs * w[i]);
}

// ---------------- RoPE tables ----------------
__global__ void rope_tab_k(float* __restrict__ ct, float* __restrict__ st) {
    int idx = blockIdx.x * 256 + threadIdx.x;  // T*32 total
    int t = idx >> 5, i = idx & 31;
    float inv = powf(10000.f, -(float)i / 32.f);
    float f = (float)t * inv;
    ct[idx] = cosf(f);
    st[idx] = sinf(f);
}

// ---------------- RoPE apply (in-place on bf16 rows) ----------------
__global__ void rope_apply_k(u16* __restrict__ x, const float* __restrict__ ct,
                             const float* __restrict__ st, int nrows, int rstride,
                             int roff, int rows_per_t) {
    int idx = blockIdx.x * 256 + threadIdx.x;
    if (idx >= nrows * 32) return;
    int row = idx >> 5, i = idx & 31;
    int t = (row / rows_per_t) % cfg::T;
    u16* p = x + (size_t)row * rstride + roff;
    float x1 = bf2f(p[i]), x2 = bf2f(p[32 + i]);
    float c = ct[t * 32 + i], s = st[t * 32 + i];
    p[i] = f2bf(x1 * c - x2 * s);
    p[32 + i] = f2bf(x2 * c + x1 * s);
}

// -------- V transpose: kv[b,t,h,128+d] -> vt[(b*H+h)*128+d][t] (bf16) --------
__global__ __launch_bounds__(256) void vtrans_k(const u16* __restrict__ kv,
                                                u16* __restrict__ vt) {
    using namespace cfg;
    __shared__ u16 tl[64][136];
    const int bh = blockIdx.x, t0 = blockIdx.y * 64;
    const int b = bh >> 4, h = bh & 15;
    const int tid = threadIdx.x;
#pragma unroll
    for (int it = 0; it < 4; ++it) {
        int id = tid + it * 256, r = id >> 4, c8 = id & 15;
        short8 v = *reinterpret_cast<const short8*>(
            kv + ((size_t)(b * T + t0 + r) * H + h) * 256 + 128 + c8 * 8);
        *reinterpret_cast<short8*>(&tl[r][c8 * 8]) = v;
    }
    __syncthreads();
#pragma unroll
    for (int it = 0; it < 4; ++it) {
        int id = tid + it * 256, d = id >> 3, tc = id & 7;
        short8 v;
#pragma unroll
        for (int j = 0; j < 8; ++j) v[j] = (short)tl[tc * 8 + j][d];
        *reinterpret_cast<short8*>(vt + ((size_t)bh * 128 + d) * T + t0 + tc * 8) = v;
    }
}

// ---------------- GEMM: C[M,N] = A[M,K] * Bt[N,K]^T (bf16 in, f32 acc) ----------------
template <int BM, int BN, int BK, int WM, int WN, bool OUTF32>
__global__ __launch_bounds__((BM / WM) * (BN / WN) * 64) void gemm_bt_k(
    const u16* __restrict__ A, const u16* __restrict__ Bt, void* __restrict__ Cv,
    int M, int N, int K) {
    constexpr int NW = (BM / WM) * (BN / WN);
    constexpr int MFR = WM / 16, NFR = WN / 16;
    constexpr int NWN = BN / WN;
    __shared__ u16 As[BM * BK];
    __shared__ u16 Bs[BN * BK];
    const int tid = threadIdx.x, lane = tid & 63, wid = tid >> 6;
    const int wr = wid / NWN, wc = wid % NWN;
    const int tM = blockIdx.x * BM, tN = blockIdx.y * BN;
    const int lr = lane & 15, hi = lane >> 4;
    f32x4 acc[MFR][NFR] = {};
    for (int k0 = 0; k0 < K; k0 += BK) {
        constexpr int ACH = BM * BK * 2 / NW;  // bytes per wave
#pragma unroll
        for (int c = 0; c < ACH / 1024; ++c) {
            int loff = wid * ACH + c * 1024;
            int eidx = (loff >> 1) + lane * 8;
            const u16* src = A + (size_t)(tM + eidx / BK) * K + k0 + (eidx % BK);
            __builtin_amdgcn_global_load_lds(
                (const __attribute__((address_space(1))) void*)src,
                (__attribute__((address_space(3))) void*)((char*)As + loff), 16, 0, 0);
        }
        constexpr int BCH = BN * BK * 2 / NW;
#pragma unroll
        for (int c = 0; c < BCH / 1024; ++c) {
            int loff = wid * BCH + c * 1024;
            int eidx = (loff >> 1) + lane * 8;
            const u16* src = Bt + (size_t)(tN + eidx / BK) * K + k0 + (eidx % BK);
            __builtin_amdgcn_global_load_lds(
                (const __attribute__((address_space(1))) void*)src,
                (__attribute__((address_space(3))) void*)((char*)Bs + loff), 16, 0, 0);
        }
        __syncthreads();
#pragma unroll
        for (int kk = 0; kk < BK / 32; ++kk) {
            bf16x8 af[MFR], bfv[NFR];
#pragma unroll
            for (int mi = 0; mi < MFR; ++mi)
                af[mi] = *reinterpret_cast<const bf16x8*>(&As[(wr * WM + mi * 16 + lr) * BK + kk * 32 + hi * 8]);
#pragma unroll
            for (int ni = 0; ni < NFR; ++ni)
                bfv[ni] = *reinterpret_cast<const bf16x8*>(&Bs[(wc * WN + ni * 16 + lr) * BK + kk * 32 + hi * 8]);
#pragma unroll
            for (int mi = 0; mi < MFR; ++mi)
#pragma unroll
                for (int ni = 0; ni < NFR; ++ni)
                    acc[mi][ni] = __builtin_amdgcn_mfma_f32_16x16x32_bf16(af[mi], bfv[ni], acc[mi][ni], 0, 0, 0);
        }
        __syncthreads();
    }
#pragma unroll
    for (int mi = 0; mi < MFR; ++mi)
#pragma unroll
        for (int ni = 0; ni < NFR; ++ni)
#pragma unroll
            for (int r = 0; r < 4; ++r) {
                int row = tM + wr * WM + mi * 16 + hi * 4 + r;
                int col = tN + wc * WN + ni * 16 + lr;
                if (OUTF32)
                    ((float*)Cv)[(size_t)row * N + col] = acc[mi][ni][r];
                else
                    ((u16*)Cv)[(size_t)row * N + col] = f2bf(acc[mi][ni][r]);
            }
}

// ---------------- Flash attention (causal, bf16, MFMA) ----------------
// QB=64, KB=64, 4 waves (16 q-rows each), paired q-tiles (j, NQT-1-j).
// V comes pre-transposed from global (vtg[(b*H+h)*128+d][t]) -> b128 staging.
// Defer-rescale (raw-unit THR=76.8 ~ 2^8 headroom) + per-lane deferred l-sum.
namespace acfg {
constexpr int QB = 64, KB = 64, KS = 200, VTS = 72, PS = 72;
constexpr int NQT = cfg::T / QB;  // 32
}
__global__ __launch_bounds__(256) void mla_attn_k(const u16* __restrict__ q,
                                                  const u16* __restrict__ kv,
                                                  const u16* __restrict__ kr, int krs,
                                                  const u16* __restrict__ vtg,
                                                  u16* __restrict__ o) {
    using namespace cfg;
    using namespace acfg;
    __shared__ u16 Ks[KB * KS];       // 64 x 192 (stride 200)
    __shared__ u16 Vt[DV * VTS];      // 128 x 64 (stride 72), already transposed
    __shared__ u16 Pl[4 * 16 * PS];   // per-wave 16 x 64 (stride 72)
    const int b = blockIdx.x >> 4, h = blockIdx.x & 15;
    const int pj = blockIdx.y;  // 0..NQT/2-1
    const int tid = threadIdx.x, lane = tid & 63, w = tid >> 6;
    const int lr = lane & 15, hi = lane >> 4;
    const float sc2 = 0.07216878364870323f * 1.4426950408889634f;  // 1/sqrt(192)*log2(e)

#pragma unroll 1
    for (int half = 0; half < 2; ++half) {
        const int qt = half ? (NQT - 1 - pj) : pj;
        const int q0 = qt * QB;
        bf16x8 qf[6];
        {
            int row = q0 + w * 16 + lr;
            const u16* qp = q + ((size_t)(b * T + row) * H + h) * DQK;
#pragma unroll
            for (int ks = 0; ks < 6; ++ks)
                qf[ks] = *reinterpret_cast<const bf16x8*>(qp + ks * 32 + hi * 8);
        }
        f32x4 oacc[8] = {};
        float mrow[4], lsum[4];
#pragma unroll
        for (int r = 0; r < 4; ++r) { mrow[r] = -INFINITY; lsum[r] = 0.f; }

        const int nkb = qt + 1;
#pragma unroll 1
        for (int kb = 0; kb < nkb; ++kb) {
            const int kt0 = kb * KB;
            // stage K nope part (64 rows x 128)
#pragma unroll
            for (int it = 0; it < 4; ++it) {
                int id = tid + it * 256, r = id >> 4, c8 = id & 15;
                short8 v = *reinterpret_cast<const short8*>(
                    kv + ((size_t)(b * T + kt0 + r) * H + h) * 256 + c8 * 8);
                *reinterpret_cast<short8*>(&Ks[r * KS + c8 * 8]) = v;
            }
            // stage K rope part (64 rows x 64)
#pragma unroll
            for (int it = 0; it < 2; ++it) {
                int id = tid + it * 256, r = id >> 3, c8 = id & 7;
                short8 v = *reinterpret_cast<const short8*>(
                    kr + (size_t)(b * T + kt0 + r) * krs + c8 * 8);
                *reinterpret_cast<short8*>(&Ks[r * KS + 128 + c8 * 8]) = v;
            }
            // stage V (already transposed in global): rows d, cols t
#pragma unroll
            for (int it = 0; it < 4; ++it) {
                int id = tid + it * 256, d = id >> 3, c8 = id & 7;
                short8 v = *reinterpret_cast<const short8*>(
                    vtg + ((size_t)(b * H + h) * 128 + d) * T + kt0 + c8 * 8);
                *reinterpret_cast<short8*>(&Vt[d * VTS + c8 * 8]) = v;
            }
            __syncthreads();

            // S = Q K^T  (per wave: 16 q-rows x 64 k-cols)
            f32x4 s[4] = {};
#pragma unroll
            for (int ks = 0; ks < 6; ++ks) {
                bf16x8 kf[4];
#pragma unroll
                for (int ni = 0; ni < 4; ++ni)
                    kf[ni] = *reinterpret_cast<const bf16x8*>(&Ks[(ni * 16 + lr) * KS + ks * 32 + hi * 8]);
#pragma unroll
                for (int ni = 0; ni < 4; ++ni)
                    s[ni] = __builtin_amdgcn_mfma_f32_16x16x32_bf16(qf[ks], kf[ni], s[ni], 0, 0, 0);
            }
            const bool diag = (kb == nkb - 1);
#pragma unroll
            for (int r = 0; r < 4; ++r) {
                float mx = -INFINITY;
#pragma unroll
                for (int ni = 0; ni < 4; ++ni) {
                    float v = s[ni][r];
                    if (diag) {
                        int qr = q0 + w * 16 + hi * 4 + r;
                        int kc = kt0 + ni * 16 + lr;
                        if (kc > qr) v = -INFINITY;
                    }
                    s[ni][r] = v;
                    mx = fmaxf(mx, v);
                }
                mx = fmaxf(mx, __shfl_xor(mx, 1));
                mx = fmaxf(mx, __shfl_xor(mx, 2));
                mx = fmaxf(mx, __shfl_xor(mx, 4));
                mx = fmaxf(mx, __shfl_xor(mx, 8));
                float mold = mrow[r];
                // defer-rescale: only raise the running max when growth > 76.8
                // raw units (= 2^8 headroom on P; f32 accum tolerates)
                float mnew = (mx > mold + 76.8f) ? mx : mold;
                float sum = 0.f;
#pragma unroll
                for (int ni = 0; ni < 4; ++ni) {
                    float p = exp2f((s[ni][r] - mnew) * sc2);
                    s[ni][r] = p;
                    sum += p;
                }
                if (mnew != mold) {
                    float alpha = exp2f((mold - mnew) * sc2);
                    lsum[r] = lsum[r] * alpha + sum;
                    mrow[r] = mnew;
#pragma unroll
                    for (int ni = 0; ni < 8; ++ni) oacc[ni][r] *= alpha;
                } else {
                    lsum[r] += sum;
                }
            }
            // write P (bf16) to per-wave LDS, re-fragment for PV
            u16* pw = &Pl[w * 16 * PS];
#pragma unroll
            for (int ni = 0; ni < 4; ++ni)
#pragma unroll
                for (int r = 0; r < 4; ++r)
                    pw[(hi * 4 + r) * PS + ni * 16 + lr] = f2bf(s[ni][r]);
            // PV
#pragma unroll
            for (int kk = 0; kk < 2; ++kk) {
                bf16x8 pf = *reinterpret_cast<const bf16x8*>(&pw[lr * PS + kk * 32 + hi * 8]);
#pragma unroll
                for (int ni = 0; ni < 8; ++ni) {
                    bf16x8 vf = *reinterpret_cast<const bf16x8*>(&Vt[(ni * 16 + lr) * VTS + kk * 32 + hi * 8]);
                    oacc[ni] = __builtin_amdgcn_mfma_f32_16x16x32_bf16(pf, vf, oacc[ni], 0, 0, 0);
                }
            }
            __syncthreads();
        }
        // reduce deferred per-lane l-sums across the 16-lane group
        float ltot[4];
#pragma unroll
        for (int r = 0; r < 4; ++r) {
            float sumv = lsum[r];
            sumv += __shfl_xor(sumv, 1);
            sumv += __shfl_xor(sumv, 2);
            sumv += __shfl_xor(sumv, 4);
            sumv += __shfl_xor(sumv, 8);
            ltot[r] = 1.f / sumv;
        }
#pragma unroll
        for (int ni = 0; ni < 8; ++ni)
#pragma unroll
            for (int r = 0; r < 4; ++r) {
                int row = q0 + w * 16 + hi * 4 + r;
                int col = ni * 16 + lr;
                float v = oacc[ni][r] * ltot[r];
                o[((size_t)(b * T + row) * H + h) * DV + col] = f2bf(v);
            }
    }
}

// ---------------- workspace layout ----------------
namespace wso {
using namespace cfg;
constexpr size_t O_HSVT = 0;  // hs_b (stage-1 input), later aliased by vt
constexpr size_t O_WCAT = O_HSVT + (size_t)BT * D * 2;          // 16.78M
constexpr size_t O_WQB  = O_WCAT + (size_t)NCAT * D * 2;        // +8.9M
constexpr size_t O_WKVB = O_WQB  + (size_t)HD * QL * 2;         // +9.4M
constexpr size_t O_WO   = O_WKVB + (size_t)KVD * KVL * 2;       // +4.2M
constexpr size_t O_QAKR = O_WO   + (size_t)D * D * 2;           // +8.4M
constexpr size_t O_QAN  = O_QAKR + (size_t)BT * NCAT * 2;       // +17.8M
constexpr size_t O_KVAN = O_QAN;  // alias: qan dead before kvan is written
constexpr size_t O_QB   = O_QAN  + (size_t)BT * QL * 2;         // +12.6M
constexpr size_t O_KV   = O_QB   + (size_t)BT * HD * 2;         // +25.2M
constexpr size_t O_COS  = O_KV   + (size_t)BT * KVD * 2;        // +33.6M
constexpr size_t O_SIN  = O_COS  + (size_t)T * 32 * 4;
constexpr size_t O_OB   = O_SIN  + (size_t)T * 32 * 4;
}

extern "C" void kernel_launch(void* const* d_in, const int* in_sizes, int n_in,
                              void* d_out, int out_size, void* d_ws, size_t ws_size,
                              hipStream_t stream) {
    using namespace cfg;
    using namespace wso;
    (void)in_sizes; (void)n_in; (void)out_size; (void)ws_size;

    const float* hs   = (const float*)d_in[0];
    const float* Wqa  = (const float*)d_in[1];
    const float* qnw  = (const float*)d_in[2];
    const float* Wqb  = (const float*)d_in[3];
    const float* Wkr  = (const float*)d_in[4];
    const float* Wkva = (const float*)d_in[5];
    const float* kvnw = (const float*)d_in[6];
    const float* Wkvb = (const float*)d_in[7];
    const float* Wo   = (const float*)d_in[8];

    char* ws = (char*)d_ws;
    u16* hs_b   = (u16*)(ws + O_HSVT);
    u16* vtg    = (u16*)(ws + O_HSVT);  // alias: hs_b dead after stage-1 GEMM
    u16* wcat   = (u16*)(ws + O_WCAT);
    u16* wqb_t  = (u16*)(ws + O_WQB);
    u16* wkvb_t = (u16*)(ws + O_WKVB);
    u16* wo_t   = (u16*)(ws + O_WO);
    u16* qakr   = (u16*)(ws + O_QAKR);
    u16* qan    = (u16*)(ws + O_QAN);
    u16* kvan   = (u16*)(ws + O_KVAN);
    u16* qb     = (u16*)(ws + O_QB);
    u16* kvb    = (u16*)(ws + O_KV);
    float* cost = (float*)(ws + O_COS);
    float* sint = (float*)(ws + O_SIN);
    u16* ob     = (u16*)(ws + O_OB);

    // 1. convert hidden to bf16
    cvt_bf16_k<<<2048, 256, 0, stream>>>(hs, hs_b, BT * D / 4);
    // 2. transpose-convert weights; wcat = [Wq_a | Wkv_a | Wk_rope]^T rows
    transpose_cvt_k<<<dim3(QL / 32, D / 32), 256, 0, stream>>>(Wqa, wcat, D, QL);
    transpose_cvt_k<<<dim3(KVL / 32, D / 32), 256, 0, stream>>>(Wkva, wcat + (size_t)QL * D, D, KVL);
    transpose_cvt_k<<<dim3(DROPE / 32, D / 32), 256, 0, stream>>>(Wkr, wcat + (size_t)(QL + KVL) * D, D, DROPE);
    transpose_cvt_k<<<dim3(HD / 32, QL / 32), 256, 0, stream>>>(Wqb, wqb_t, QL, HD);
    transpose_cvt_k<<<dim3(KVD / 32, KVL / 32), 256, 0, stream>>>(Wkvb, wkvb_t, KVL, KVD);
    transpose_cvt_k<<<dim3(D / 32, D / 32), 256, 0, stream>>>(Wo, wo_t, D, D);
    // 3. rope tables
    rope_tab_k<<<T * 32 / 256, 256, 0, stream>>>(cost, sint);
    // 4. fused stage-1: qakr = hidden @ [Wq_a|Wkv_a|Wk_rope]  (32x17 = 544 wgs)
    gemm_bt_k<128, 128, 32, 64, 64, false><<<dim3(BT / 128, NCAT / 128), 256, 0, stream>>>(
        hs_b, wcat, qakr, BT, NCAT, D);
    // 5. q branch: rmsnorm -> q_b -> rope
    rmsnorm_k<<<BT, 256, 0, stream>>>(qakr, qnw, qan, QL, NCAT);
    gemm_bt_k<128, 128, 32, 64, 64, false><<<dim3(BT / 128, HD / 128), 256, 0, stream>>>(
        qan, wqb_t, qb, BT, HD, QL);
    rope_apply_k<<<BT * H * 32 / 256, 256, 0, stream>>>(qb, cost, sint, BT * H, DQK, 128, H);
    // 6. kv branch: rmsnorm -> kv_b
    rmsnorm_k<<<BT, 256, 0, stream>>>(qakr + QL, kvnw, kvan, KVL, NCAT);
    gemm_bt_k<128, 128, 32, 64, 64, false><<<dim3(BT / 128, KVD / 128), 256, 0, stream>>>(
        kvan, wkvb_t, kvb, BT, KVD, KVL);
    // 7. rope on k_rope slice (in place in qakr)
    rope_apply_k<<<BT * 32 / 256, 256, 0, stream>>>(qakr + QL + KVL, cost, sint, BT, NCAT, 0, 1);
    // 8. global V transpose, then attention
    vtrans_k<<<dim3(B * H, T / 64), 256, 0, stream>>>(kvb, vtg);
    mla_attn_k<<<dim3(B * H, acfg::NQT / 2), 256, 0, stream>>>(qb, kvb, qakr + QL + KVL, NCAT, vtg, ob);
    // 9. out = o @ Wo  (f32 out)
    gemm_bt_k<128, 128, 32, 64, 64, true><<<dim3(BT / 128, D / 128), 256, 0, stream>>>(
        ob, wo_t, d_out, BT, D, H * DV);
}